// Round 3
// baseline (4749.128 us; speedup 1.0000x reference)
//
#include <hip/hip_runtime.h>
#include <hip/hip_bf16.h>

#define IN_F  128
#define HID_F 256
#define OUT_F 64

__device__ __forceinline__ float bf2f(unsigned short u) {
    union { unsigned int i; float f; } v; v.i = ((unsigned int)u) << 16; return v.f;
}
__device__ __forceinline__ unsigned short f2bf(float f) {
    __hip_bfloat16 b = __float2bfloat16(f);
    return *reinterpret_cast<unsigned short*>(&b);
}

// Layer-1 scatter: agg1[dst] += x[src]. 32 threads/edge, 4 fp32 each.
__global__ __launch_bounds__(256) void scatter_f32(
    const float* __restrict__ h,
    const int* __restrict__ src, const int* __restrict__ dst,
    float* __restrict__ agg, int nEdges)
{
    long long i = (long long)blockIdx.x * blockDim.x + threadIdx.x;
    long long total = (long long)nEdges * (IN_F / 4);
    if (i >= total) return;
    int e = (int)(i >> 5);
    int c = ((int)i & 31) * 4;
    int s = src[e];
    int d = dst[e];
    float4 v = *reinterpret_cast<const float4*>(h + (size_t)s * IN_F + c);
    float* a = agg + (size_t)d * IN_F + c;
    unsafeAtomicAdd(a + 0, v.x);
    unsafeAtomicAdd(a + 1, v.y);
    unsafeAtomicAdd(a + 2, v.z);
    unsafeAtomicAdd(a + 3, v.w);
}

// Layer-2 scatter (commuted form): out[dst] += z[src]. 16 threads/edge, 4 fp32 each.
__global__ __launch_bounds__(256) void scatter_z(
    const float* __restrict__ z,
    const int* __restrict__ src, const int* __restrict__ dst,
    float* __restrict__ out, int nEdges)
{
    long long i = (long long)blockIdx.x * blockDim.x + threadIdx.x;
    long long total = (long long)nEdges * (OUT_F / 4);
    if (i >= total) return;
    int e = (int)(i >> 4);
    int c = ((int)i & 15) * 4;
    int s = src[e];
    int d = dst[e];
    float4 v = *reinterpret_cast<const float4*>(z + (size_t)s * OUT_F + c);
    float* a = out + (size_t)d * OUT_F + c;
    unsafeAtomicAdd(a + 0, v.x);
    unsafeAtomicAdd(a + 1, v.y);
    unsafeAtomicAdd(a + 2, v.z);
    unsafeAtomicAdd(a + 3, v.w);
}

// h1[n,j] = sum_k (x[n,k] + agg1[n,k]) * W1[k,j]; j = threadIdx.x (256 outputs/node)
__global__ __launch_bounds__(256) void gemm1(
    const float* __restrict__ x, const float* __restrict__ agg,
    const float* __restrict__ W, unsigned short* __restrict__ h1,
    int nNodes)
{
    __shared__ unsigned short Wl[IN_F * HID_F];  // 64 KB, W1 rounded to bf16
    __shared__ float row[IN_F];
    const int t = threadIdx.x;
    for (int i = t; i < IN_F * HID_F; i += 256)
        Wl[i] = f2bf(W[i]);
    __syncthreads();
    for (int n = blockIdx.x; n < nNodes; n += gridDim.x) {
        if (t < IN_F)
            row[t] = x[(size_t)n * IN_F + t] + agg[(size_t)n * IN_F + t];
        __syncthreads();
        float acc = 0.f;
        #pragma unroll 8
        for (int k = 0; k < IN_F; ++k)
            acc = fmaf(row[k], bf2f(Wl[k * HID_F + t]), acc);
        h1[(size_t)n * HID_F + t] = f2bf(acc);
        __syncthreads();
    }
}

// z[n,j] = sum_k h1[n,k] * W2[k,j]; also seeds out[n,j] = z[n,j] (self term).
// 4 nodes per block iter, 64 outputs each.
__global__ __launch_bounds__(256) void gemm2z(
    const unsigned short* __restrict__ h1,
    const float* __restrict__ W, float* __restrict__ z,
    float* __restrict__ out, int nNodes)
{
    __shared__ float Wl[HID_F * OUT_F]; // 64 KB fp32
    __shared__ float rows[4][HID_F];    // 4 KB
    const int t = threadIdx.x;
    for (int i = t; i < HID_F * OUT_F / 4; i += 256)
        reinterpret_cast<float4*>(Wl)[i] = reinterpret_cast<const float4*>(W)[i];
    __syncthreads();
    for (int n0 = blockIdx.x * 4; n0 < nNodes; n0 += gridDim.x * 4) {
        for (int i = t; i < 4 * HID_F; i += 256) {
            int m = i >> 8, k = i & (HID_F - 1);
            int n = n0 + m;
            rows[m][k] = (n < nNodes) ? bf2f(h1[(size_t)n * HID_F + k]) : 0.f;
        }
        __syncthreads();
        int m = t >> 6, j = t & 63;
        int n = n0 + m;
        float acc = 0.f;
        #pragma unroll 8
        for (int k = 0; k < HID_F; ++k)
            acc = fmaf(rows[m][k], Wl[k * OUT_F + j], acc);
        if (n < nNodes) {
            z[(size_t)n * OUT_F + j] = acc;
            out[(size_t)n * OUT_F + j] = acc;   // self term; scatter_z adds agg on top
        }
        __syncthreads();
    }
}

extern "C" void kernel_launch(void* const* d_in, const int* in_sizes, int n_in,
                              void* d_out, int out_size, void* d_ws, size_t ws_size,
                              hipStream_t stream) {
    const float* x  = (const float*)d_in[0];
    const int* esrc = (const int*)d_in[1];
    const int* edst = (const int*)d_in[2];
    const float* W1 = (const float*)d_in[3];
    const float* W2 = (const float*)d_in[4];
    float* out      = (float*)d_out;

    const int nNodes = in_sizes[0] / IN_F;
    const int nEdges = in_sizes[1];

    // Workspace layout (peak 102.4 MB — R1's 204.8 MB overran ws_size and
    // stomped the harness's pristine input copies):
    //   [0, agg1_b)          agg1 fp32 [N,128]   (live: scatter_f32 .. gemm1)
    //   [0, z_b)             z    fp32 [N,64]    (aliases agg1; live after gemm1)
    //   [agg1_b, +h1_b)      h1   bf16 [N,256]
    char* ws = (char*)d_ws;
    const size_t agg1_b = (size_t)nNodes * IN_F * sizeof(float);   // 51.2 MB
    float* agg1 = (float*)ws;
    float* z    = (float*)ws;                                      // alias, 25.6 MB
    unsigned short* h1 = (unsigned short*)(ws + agg1_b);           // bf16, 51.2 MB

    // agg1 must start from zero; d_ws is poisoned 0xAA before every call.
    hipMemsetAsync(agg1, 0, agg1_b, stream);

    long long t1 = (long long)nEdges * (IN_F / 4);
    scatter_f32<<<(int)((t1 + 255) / 256), 256, 0, stream>>>(
        x, esrc, edst, agg1, nEdges);

    gemm1<<<1024, 256, 0, stream>>>(x, agg1, W1, h1, nNodes);

    gemm2z<<<1024, 256, 0, stream>>>(h1, W2, z, out, nNodes);

    long long t2 = (long long)nEdges * (OUT_F / 4);
    scatter_z<<<(int)((t2 + 255) / 256), 256, 0, stream>>>(
        z, esrc, edst, out, nEdges);
}

// Round 4
// 1312.406 us; speedup vs baseline: 3.6186x; 3.6186x over previous
//
#include <hip/hip_runtime.h>
#include <hip/hip_bf16.h>

#define IN_F  128
#define HID_F 256
#define OUT_F 64

__device__ __forceinline__ float bf2f(unsigned short u) {
    union { unsigned int i; float f; } v; v.i = ((unsigned int)u) << 16; return v.f;
}
__device__ __forceinline__ unsigned short f2bf(float f) {
    __hip_bfloat16 b = __float2bfloat16(f);
    return *reinterpret_cast<unsigned short*>(&b);
}

// ---- CSR build ----------------------------------------------------------
__global__ __launch_bounds__(256) void k_deg(
    const int* __restrict__ dst, int* __restrict__ deg, int nEdges)
{
    int e = blockIdx.x * blockDim.x + threadIdx.x;
    if (e < nEdges) atomicAdd(&deg[dst[e]], 1);
}

// Single block, 1024 threads: exclusive scan deg -> rowptr (and cursor copy).
__global__ __launch_bounds__(1024) void k_scan(
    const int* __restrict__ deg, int* __restrict__ rowptr,
    int* __restrict__ cursor, int nNodes)
{
    __shared__ int partial[1024];
    const int t = threadIdx.x;
    const int per = (nNodes + 1023) / 1024;
    const int start = t * per;
    const int end   = min(start + per, nNodes);
    int s = 0;
    for (int i = start; i < end; ++i) s += deg[i];
    partial[t] = s;
    __syncthreads();
    for (int d = 1; d < 1024; d <<= 1) {
        int add = (t >= d) ? partial[t - d] : 0;
        __syncthreads();
        partial[t] += add;
        __syncthreads();
    }
    int off = partial[t] - s;          // exclusive prefix
    for (int i = start; i < end; ++i) {
        rowptr[i] = off;
        cursor[i] = off;
        off += deg[i];
    }
    if (t == 1023) rowptr[nNodes] = partial[1023];
}

__global__ __launch_bounds__(256) void k_place(
    const int* __restrict__ src, const int* __restrict__ dst,
    int* __restrict__ cursor, int* __restrict__ eidx, int nEdges)
{
    int e = blockIdx.x * blockDim.x + threadIdx.x;
    if (e < nEdges) {
        int j = atomicAdd(&cursor[dst[e]], 1);
        eidx[j] = src[e];
    }
}

// ---- Layer-1 gather: agg[n] = x[n] + sum x[src], bf16 out ---------------
// One wave per node; lane holds features {2*lane, 2*lane+1}.
__global__ __launch_bounds__(256) void gather1(
    const float* __restrict__ x, const int* __restrict__ rowptr,
    const int* __restrict__ eidx, unsigned short* __restrict__ agg, int nNodes)
{
    int n    = blockIdx.x * 4 + (threadIdx.x >> 6);
    int lane = threadIdx.x & 63;
    if (n >= nNodes) return;
    int beg = rowptr[n], end = rowptr[n + 1];
    float2 acc = *reinterpret_cast<const float2*>(x + (size_t)n * IN_F + lane * 2);
    for (int base = beg; base < end; base += 64) {
        int cnt = min(64, end - base);
        int e = (base + lane < end) ? eidx[base + lane] : 0;
        for (int i = 0; i < cnt; ++i) {
            int s = __shfl(e, i);
            float2 v = *reinterpret_cast<const float2*>(x + (size_t)s * IN_F + lane * 2);
            acc.x += v.x; acc.y += v.y;
        }
    }
    unsigned int p = (unsigned int)f2bf(acc.x) | ((unsigned int)f2bf(acc.y) << 16);
    *reinterpret_cast<unsigned int*>(agg + (size_t)n * IN_F + lane * 2) = p;
}

// ---- Layer-2 gather (commuted): out[n] = z[n] + sum z[src] --------------
__global__ __launch_bounds__(256) void gather2(
    const float* __restrict__ z, const int* __restrict__ rowptr,
    const int* __restrict__ eidx, float* __restrict__ out, int nNodes)
{
    int n    = blockIdx.x * 4 + (threadIdx.x >> 6);
    int lane = threadIdx.x & 63;
    if (n >= nNodes) return;
    int beg = rowptr[n], end = rowptr[n + 1];
    float acc = z[(size_t)n * OUT_F + lane];
    for (int base = beg; base < end; base += 64) {
        int cnt = min(64, end - base);
        int e = (base + lane < end) ? eidx[base + lane] : 0;
        for (int i = 0; i < cnt; ++i) {
            int s = __shfl(e, i);
            acc += z[(size_t)s * OUT_F + lane];
        }
    }
    out[(size_t)n * OUT_F + lane] = acc;
}

// ---- GEMM1: h1[n,j] = sum_k agg[n,k]*W1[k,j] ----------------------------
__global__ __launch_bounds__(256) void gemm1(
    const unsigned short* __restrict__ agg,
    const float* __restrict__ W, unsigned short* __restrict__ h1,
    int nNodes)
{
    __shared__ unsigned short Wl[IN_F * HID_F];  // 64 KB bf16
    __shared__ float row[IN_F];
    const int t = threadIdx.x;
    for (int i = t; i < IN_F * HID_F; i += 256)
        Wl[i] = f2bf(W[i]);
    __syncthreads();
    for (int n = blockIdx.x; n < nNodes; n += gridDim.x) {
        if (t < IN_F)
            row[t] = bf2f(agg[(size_t)n * IN_F + t]);
        __syncthreads();
        float acc = 0.f;
        #pragma unroll 8
        for (int k = 0; k < IN_F; ++k)
            acc = fmaf(row[k], bf2f(Wl[k * HID_F + t]), acc);
        h1[(size_t)n * HID_F + t] = f2bf(acc);
        __syncthreads();
    }
}

// ---- GEMM2: z[n,j] = sum_k h1[n,k]*W2[k,j] ------------------------------
__global__ __launch_bounds__(256) void gemm2z(
    const unsigned short* __restrict__ h1,
    const float* __restrict__ W, float* __restrict__ z, int nNodes)
{
    __shared__ float Wl[HID_F * OUT_F]; // 64 KB fp32
    __shared__ float rows[4][HID_F];    // 4 KB
    const int t = threadIdx.x;
    for (int i = t; i < HID_F * OUT_F / 4; i += 256)
        reinterpret_cast<float4*>(Wl)[i] = reinterpret_cast<const float4*>(W)[i];
    __syncthreads();
    for (int n0 = blockIdx.x * 4; n0 < nNodes; n0 += gridDim.x * 4) {
        for (int i = t; i < 4 * HID_F; i += 256) {
            int m = i >> 8, k = i & (HID_F - 1);
            int n = n0 + m;
            rows[m][k] = (n < nNodes) ? bf2f(h1[(size_t)n * HID_F + k]) : 0.f;
        }
        __syncthreads();
        int m = t >> 6, j = t & 63;
        int n = n0 + m;
        float acc = 0.f;
        #pragma unroll 8
        for (int k = 0; k < HID_F; ++k)
            acc = fmaf(rows[m][k], Wl[k * OUT_F + j], acc);
        if (n < nNodes) z[(size_t)n * OUT_F + j] = acc;
        __syncthreads();
    }
}

extern "C" void kernel_launch(void* const* d_in, const int* in_sizes, int n_in,
                              void* d_out, int out_size, void* d_ws, size_t ws_size,
                              hipStream_t stream) {
    const float* x  = (const float*)d_in[0];
    const int* esrc = (const int*)d_in[1];
    const int* edst = (const int*)d_in[2];
    const float* W1 = (const float*)d_in[3];
    const float* W2 = (const float*)d_in[4];
    float* out      = (float*)d_out;

    const int nNodes = in_sizes[0] / IN_F;
    const int nEdges = in_sizes[1];

    // Workspace layout (~86 MB; 102.4 MB is known-safe, 204.8 was not):
    //   [0, h1_b)        h1   bf16 [N,256]                     51.2 MB
    //   [h1_b, +25.6M)   agg  bf16 [N,128]  -- then aliased by
    //                    z    fp32 [N,64]   (agg dead after gemm1)
    //   then eidx int[E], rowptr int[N+1], cursor int[N], deg int[N]
    char* ws = (char*)d_ws;
    const size_t h1_b   = (size_t)nNodes * HID_F * sizeof(unsigned short); // 51.2 MB
    const size_t aggz_b = (size_t)nNodes * IN_F * sizeof(unsigned short);  // 25.6 MB (== N*64*4)
    unsigned short* h1  = (unsigned short*)ws;
    unsigned short* agg = (unsigned short*)(ws + h1_b);
    float*          z   = (float*)(ws + h1_b);                  // alias of agg
    int* eidx   = (int*)(ws + h1_b + aggz_b);
    int* rowptr = eidx + nEdges;
    int* cursor = rowptr + (nNodes + 1);
    int* deg    = cursor + nNodes;

    // deg must start at zero (ws is poisoned 0xAA each call).
    hipMemsetAsync(deg, 0, (size_t)nNodes * sizeof(int), stream);

    const int eBlocks = (nEdges + 255) / 256;
    k_deg<<<eBlocks, 256, 0, stream>>>(edst, deg, nEdges);
    k_scan<<<1, 1024, 0, stream>>>(deg, rowptr, cursor, nNodes);
    k_place<<<eBlocks, 256, 0, stream>>>(esrc, edst, cursor, eidx, nEdges);

    const int nBlocks = (nNodes + 3) / 4;
    gather1<<<nBlocks, 256, 0, stream>>>(x, rowptr, eidx, agg, nNodes);
    gemm1<<<1024, 256, 0, stream>>>(agg, W1, h1, nNodes);
    gemm2z<<<1024, 256, 0, stream>>>(h1, W2, z, nNodes);
    gather2<<<nBlocks, 256, 0, stream>>>(z, rowptr, eidx, out, nNodes);
}

// Round 5
// 802.701 us; speedup vs baseline: 5.9164x; 1.6350x over previous
//
#include <hip/hip_runtime.h>
#include <hip/hip_bf16.h>

#define IN_F  128
#define HID_F 256
#define OUT_F 64

typedef __attribute__((ext_vector_type(8))) short bf16x8;
typedef __attribute__((ext_vector_type(4))) float f32x4;

__device__ __forceinline__ float bf2f(unsigned short u) {
    union { unsigned int i; float f; } v; v.i = ((unsigned int)u) << 16; return v.f;
}
__device__ __forceinline__ unsigned short f2bf(float f) {
    __hip_bfloat16 b = __float2bfloat16(f);
    return *reinterpret_cast<unsigned short*>(&b);
}

// ---- CSR build ----------------------------------------------------------
__global__ __launch_bounds__(256) void k_deg(
    const int* __restrict__ dst, int* __restrict__ deg, int nEdges)
{
    int e = blockIdx.x * blockDim.x + threadIdx.x;
    if (e < nEdges) atomicAdd(&deg[dst[e]], 1);
}

__global__ __launch_bounds__(1024) void k_scan(
    const int* __restrict__ deg, int* __restrict__ rowptr,
    int* __restrict__ cursor, int nNodes)
{
    __shared__ int partial[1024];
    const int t = threadIdx.x;
    const int per = (nNodes + 1023) / 1024;
    const int start = t * per;
    const int end   = min(start + per, nNodes);
    int s = 0;
    for (int i = start; i < end; ++i) s += deg[i];
    partial[t] = s;
    __syncthreads();
    for (int d = 1; d < 1024; d <<= 1) {
        int add = (t >= d) ? partial[t - d] : 0;
        __syncthreads();
        partial[t] += add;
        __syncthreads();
    }
    int off = partial[t] - s;
    for (int i = start; i < end; ++i) {
        rowptr[i] = off;
        cursor[i] = off;
        off += deg[i];
    }
    if (t == 1023) rowptr[nNodes] = partial[1023];
}

__global__ __launch_bounds__(256) void k_place(
    const int* __restrict__ src, const int* __restrict__ dst,
    int* __restrict__ cursor, int* __restrict__ eidx, int nEdges)
{
    int e = blockIdx.x * blockDim.x + threadIdx.x;
    if (e < nEdges) {
        int j = atomicAdd(&cursor[dst[e]], 1);
        eidx[j] = src[e];
    }
}

// ---- Weight swizzle: fp32 W -> bf16 in B-fragment order -----------------
// mfma_f32_16x16x32_bf16 B-frag: lane L holds B[k=(L>>4)*8+j][n=(L&15)], j=0..7.
// Chunk c covers (ntile, kstep); linear: ws[c*512 + L*8 + j].
__global__ __launch_bounds__(256) void k_wconv(
    const float* __restrict__ W1, const float* __restrict__ W2,
    unsigned short* __restrict__ w1s, unsigned short* __restrict__ w2s)
{
    int idx = blockIdx.x * blockDim.x + threadIdx.x;
    if (idx < IN_F * HID_F) {            // W1: 16 ntiles x 4 ksteps
        int c = idx >> 9, L = (idx >> 3) & 63, j = idx & 7;
        int ntile = c >> 2, kstep = c & 3;
        int k = kstep * 32 + (L >> 4) * 8 + j;
        int n = ntile * 16 + (L & 15);
        w1s[idx] = f2bf(W1[k * HID_F + n]);
    }
    if (idx < HID_F * OUT_F) {           // W2: 4 ntiles x 8 ksteps
        int c = idx >> 9, L = (idx >> 3) & 63, j = idx & 7;
        int ntile = c >> 3, kstep = c & 7;
        int k = kstep * 32 + (L >> 4) * 8 + j;
        int n = ntile * 16 + (L & 15);
        w2s[idx] = f2bf(W2[k * OUT_F + n]);
    }
}

// ---- Layer-1 gather: agg[n] = x[n] + sum x[src], bf16 out ---------------
__global__ __launch_bounds__(256) void gather1(
    const float* __restrict__ x, const int* __restrict__ rowptr,
    const int* __restrict__ eidx, unsigned short* __restrict__ agg, int nNodes)
{
    int n    = blockIdx.x * 4 + (threadIdx.x >> 6);
    int lane = threadIdx.x & 63;
    if (n >= nNodes) return;
    int beg = rowptr[n], end = rowptr[n + 1];
    float2 acc = *reinterpret_cast<const float2*>(x + (size_t)n * IN_F + lane * 2);
    for (int base = beg; base < end; base += 64) {
        int cnt = min(64, end - base);
        int e = (base + lane < end) ? eidx[base + lane] : 0;
        for (int i = 0; i < cnt; ++i) {
            int s = __shfl(e, i);
            float2 v = *reinterpret_cast<const float2*>(x + (size_t)s * IN_F + lane * 2);
            acc.x += v.x; acc.y += v.y;
        }
    }
    unsigned int p = (unsigned int)f2bf(acc.x) | ((unsigned int)f2bf(acc.y) << 16);
    *reinterpret_cast<unsigned int*>(agg + (size_t)n * IN_F + lane * 2) = p;
}

// ---- GEMM1 (MFMA): h1[M,256] = agg[M,128] @ W1, bf16 out ----------------
// Wave handles 16 rows x 256 cols. No LDS.
__global__ __launch_bounds__(256) void gemm1_mfma(
    const unsigned short* __restrict__ agg, const unsigned short* __restrict__ w1s,
    unsigned short* __restrict__ h1, int nNodes)
{
    int wave = threadIdx.x >> 6, lane = threadIdx.x & 63;
    int m0 = blockIdx.x * 64 + wave * 16;
    if (m0 >= nNodes) return;
    int row = lane & 15, quad = lane >> 4;
    f32x4 acc[16] = {};
    const bf16x8* aBase = reinterpret_cast<const bf16x8*>(
        agg + (size_t)(m0 + row) * IN_F + quad * 8);
    const bf16x8* bBase = reinterpret_cast<const bf16x8*>(w1s) + lane;
    #pragma unroll
    for (int ks = 0; ks < 4; ++ks) {
        bf16x8 a = aBase[ks * 4];                 // k = ks*32 + quad*8 ..
        #pragma unroll
        for (int nt = 0; nt < 16; ++nt) {
            bf16x8 b = bBase[(nt * 4 + ks) * 64];
            acc[nt] = __builtin_amdgcn_mfma_f32_16x16x32_bf16(a, b, acc[nt], 0, 0, 0);
        }
    }
    // D: lane holds D[quad*4+i][nt*16+row]
    size_t outBase = (size_t)(m0 + quad * 4) * HID_F + row;
    #pragma unroll
    for (int nt = 0; nt < 16; ++nt)
        #pragma unroll
        for (int i = 0; i < 4; ++i)
            h1[outBase + (size_t)i * HID_F + nt * 16] = f2bf(acc[nt][i]);
}

// ---- GEMM2 (MFMA): z[M,64] = h1[M,256] @ W2, bf16 out -------------------
__global__ __launch_bounds__(256) void gemm2_mfma(
    const unsigned short* __restrict__ h1, const unsigned short* __restrict__ w2s,
    unsigned short* __restrict__ z, int nNodes)
{
    int wave = threadIdx.x >> 6, lane = threadIdx.x & 63;
    int m0 = blockIdx.x * 64 + wave * 16;
    if (m0 >= nNodes) return;
    int row = lane & 15, quad = lane >> 4;
    f32x4 acc[4] = {};
    const bf16x8* aBase = reinterpret_cast<const bf16x8*>(
        h1 + (size_t)(m0 + row) * HID_F + quad * 8);
    const bf16x8* bBase = reinterpret_cast<const bf16x8*>(w2s) + lane;
    #pragma unroll
    for (int ks = 0; ks < 8; ++ks) {
        bf16x8 a = aBase[ks * 4];
        #pragma unroll
        for (int nt = 0; nt < 4; ++nt) {
            bf16x8 b = bBase[(nt * 8 + ks) * 64];
            acc[nt] = __builtin_amdgcn_mfma_f32_16x16x32_bf16(a, b, acc[nt], 0, 0, 0);
        }
    }
    size_t outBase = (size_t)(m0 + quad * 4) * OUT_F + row;
    #pragma unroll
    for (int nt = 0; nt < 4; ++nt)
        #pragma unroll
        for (int i = 0; i < 4; ++i)
            z[outBase + (size_t)i * OUT_F + nt * 16] = f2bf(acc[nt][i]);
}

// ---- Layer-2 gather (commuted): out[n] = z[n] + sum z[src] --------------
__global__ __launch_bounds__(256) void gather2(
    const unsigned short* __restrict__ z, const int* __restrict__ rowptr,
    const int* __restrict__ eidx, float* __restrict__ out, int nNodes)
{
    int n    = blockIdx.x * 4 + (threadIdx.x >> 6);
    int lane = threadIdx.x & 63;
    if (n >= nNodes) return;
    int beg = rowptr[n], end = rowptr[n + 1];
    float acc = bf2f(z[(size_t)n * OUT_F + lane]);
    for (int base = beg; base < end; base += 64) {
        int cnt = min(64, end - base);
        int e = (base + lane < end) ? eidx[base + lane] : 0;
        for (int i = 0; i < cnt; ++i) {
            int s = __shfl(e, i);
            acc += bf2f(z[(size_t)s * OUT_F + lane]);
        }
    }
    out[(size_t)n * OUT_F + lane] = acc;
}

extern "C" void kernel_launch(void* const* d_in, const int* in_sizes, int n_in,
                              void* d_out, int out_size, void* d_ws, size_t ws_size,
                              hipStream_t stream) {
    const float* x  = (const float*)d_in[0];
    const int* esrc = (const int*)d_in[1];
    const int* edst = (const int*)d_in[2];
    const float* W1 = (const float*)d_in[3];
    const float* W2 = (const float*)d_in[4];
    float* out      = (float*)d_out;

    const int nNodes = in_sizes[0] / IN_F;
    const int nEdges = in_sizes[1];

    // Workspace (~84.5 MB; 102.4 MB known-safe):
    //   h1 bf16 [N,256]                              51.2 MB
    //   agg bf16 [N,128] / z bf16 [N,64] (alias)     25.6 MB
    //   eidx int[E]                                   6.4 MB
    //   w1s bf16 32768 (16B-aligned), w2s bf16 16384  96 KB
    //   rowptr int[N+1], cursor int[N], deg int[N]    1.2 MB
    char* ws = (char*)d_ws;
    const size_t h1_b   = (size_t)nNodes * HID_F * sizeof(unsigned short);
    const size_t aggz_b = (size_t)nNodes * IN_F * sizeof(unsigned short);
    const size_t eidx_b = (size_t)nEdges * sizeof(int);
    unsigned short* h1  = (unsigned short*)ws;
    unsigned short* agg = (unsigned short*)(ws + h1_b);
    unsigned short* z   = (unsigned short*)(ws + h1_b);          // alias of agg
    int* eidx           = (int*)(ws + h1_b + aggz_b);
    unsigned short* w1s = (unsigned short*)(ws + h1_b + aggz_b + eidx_b);
    unsigned short* w2s = w1s + IN_F * HID_F;
    int* rowptr = (int*)(w2s + HID_F * OUT_F);
    int* cursor = rowptr + (nNodes + 1);
    int* deg    = cursor + nNodes;

    hipMemsetAsync(deg, 0, (size_t)nNodes * sizeof(int), stream);

    k_wconv<<<(IN_F * HID_F + 255) / 256, 256, 0, stream>>>(W1, W2, w1s, w2s);

    const int eBlocks = (nEdges + 255) / 256;
    k_deg<<<eBlocks, 256, 0, stream>>>(edst, deg, nEdges);
    k_scan<<<1, 1024, 0, stream>>>(deg, rowptr, cursor, nNodes);
    k_place<<<eBlocks, 256, 0, stream>>>(esrc, edst, cursor, eidx, nEdges);

    const int nBlocks = (nNodes + 3) / 4;
    const int mBlocks = (nNodes + 63) / 64;
    gather1<<<nBlocks, 256, 0, stream>>>(x, rowptr, eidx, agg, nNodes);
    gemm1_mfma<<<mBlocks, 256, 0, stream>>>(agg, w1s, h1, nNodes);
    gemm2_mfma<<<mBlocks, 256, 0, stream>>>(h1, w2s, z, nNodes);
    gather2<<<nBlocks, 256, 0, stream>>>(z, rowptr, eidx, out, nNodes);
}

// Round 6
// 580.333 us; speedup vs baseline: 8.1835x; 1.3832x over previous
//
#include <hip/hip_runtime.h>
#include <hip/hip_bf16.h>

#define IN_F  128
#define HID_F 256
#define OUT_F 64
#define SCAN_B 512   // deg elements per scan block (2 per thread, 256 threads)

typedef __attribute__((ext_vector_type(8))) short bf16x8;
typedef __attribute__((ext_vector_type(4))) float f32x4;

__device__ __forceinline__ float bf2f(unsigned short u) {
    union { unsigned int i; float f; } v; v.i = ((unsigned int)u) << 16; return v.f;
}
__device__ __forceinline__ unsigned short f2bf(float f) {
    __hip_bfloat16 b = __float2bfloat16(f);
    return *reinterpret_cast<unsigned short*>(&b);
}

// ---- CSR build ----------------------------------------------------------
__global__ __launch_bounds__(256) void k_deg(
    const int* __restrict__ dst, int* __restrict__ deg, int nEdges)
{
    int e = blockIdx.x * blockDim.x + threadIdx.x;
    if (e < nEdges) atomicAdd(&deg[dst[e]], 1);
}

// Phase 1: per-block sums of 512-element chunks.
__global__ __launch_bounds__(256) void k_bsum(
    const int* __restrict__ deg, int* __restrict__ bsum, int nNodes)
{
    __shared__ int sh[256];
    int t = threadIdx.x;
    int i0 = blockIdx.x * SCAN_B + 2 * t, i1 = i0 + 1;
    int s = ((i0 < nNodes) ? deg[i0] : 0) + ((i1 < nNodes) ? deg[i1] : 0);
    sh[t] = s; __syncthreads();
    for (int d = 128; d > 0; d >>= 1) {
        if (t < d) sh[t] += sh[t + d];
        __syncthreads();
    }
    if (t == 0) bsum[blockIdx.x] = sh[0];
}

// Phase 2: single small block scans the block partials (exclusive, in place).
__global__ __launch_bounds__(256) void k_scanb(
    int* __restrict__ bsum, int* __restrict__ rowptr, int nb, int nNodes, int nEdges)
{
    __shared__ int sh[256];
    int t = threadIdx.x;
    int carry = 0;
    for (int base = 0; base < nb; base += 256) {
        int v = (base + t < nb) ? bsum[base + t] : 0;
        sh[t] = v; __syncthreads();
        for (int d = 1; d < 256; d <<= 1) {
            int add = (t >= d) ? sh[t - d] : 0;
            __syncthreads();
            sh[t] += add;
            __syncthreads();
        }
        if (base + t < nb) bsum[base + t] = carry + sh[t] - v;
        carry += sh[255];
        __syncthreads();
    }
    if (t == 0) rowptr[nNodes] = nEdges;
}

// Phase 3: per-block exclusive scan of its chunk + block offset -> rowptr/cursor.
__global__ __launch_bounds__(256) void k_emit(
    const int* __restrict__ deg, const int* __restrict__ bsum,
    int* __restrict__ rowptr, int* __restrict__ cursor, int nNodes)
{
    __shared__ int sh[256];
    int t = threadIdx.x;
    int i0 = blockIdx.x * SCAN_B + 2 * t, i1 = i0 + 1;
    int d0 = (i0 < nNodes) ? deg[i0] : 0;
    int d1 = (i1 < nNodes) ? deg[i1] : 0;
    int s = d0 + d1;
    sh[t] = s; __syncthreads();
    for (int d = 1; d < 256; d <<= 1) {
        int add = (t >= d) ? sh[t - d] : 0;
        __syncthreads();
        sh[t] += add;
        __syncthreads();
    }
    int excl = bsum[blockIdx.x] + sh[t] - s;
    if (i0 < nNodes) { rowptr[i0] = excl;      cursor[i0] = excl; }
    if (i1 < nNodes) { rowptr[i1] = excl + d0; cursor[i1] = excl + d0; }
}

__global__ __launch_bounds__(256) void k_place(
    const int* __restrict__ src, const int* __restrict__ dst,
    int* __restrict__ cursor, int* __restrict__ eidx, int nEdges)
{
    int e = blockIdx.x * blockDim.x + threadIdx.x;
    if (e < nEdges) {
        int j = atomicAdd(&cursor[dst[e]], 1);
        eidx[j] = src[e];
    }
}

// ---- Weight swizzle: fp32 W -> bf16 in B-fragment order -----------------
__global__ __launch_bounds__(256) void k_wconv(
    const float* __restrict__ W1, const float* __restrict__ W2,
    unsigned short* __restrict__ w1s, unsigned short* __restrict__ w2s)
{
    int idx = blockIdx.x * blockDim.x + threadIdx.x;
    if (idx < IN_F * HID_F) {            // W1: 16 ntiles x 4 ksteps
        int c = idx >> 9, L = (idx >> 3) & 63, j = idx & 7;
        int ntile = c >> 2, kstep = c & 3;
        int k = kstep * 32 + (L >> 4) * 8 + j;
        int n = ntile * 16 + (L & 15);
        w1s[idx] = f2bf(W1[k * HID_F + n]);
    }
    if (idx < HID_F * OUT_F) {           // W2: 4 ntiles x 8 ksteps
        int c = idx >> 9, L = (idx >> 3) & 63, j = idx & 7;
        int ntile = c >> 3, kstep = c & 7;
        int k = kstep * 32 + (L >> 4) * 8 + j;
        int n = ntile * 16 + (L & 15);
        w2s[idx] = f2bf(W2[k * OUT_F + n]);
    }
}

// ---- Layer-1 gather: agg[n] = x[n] + sum x[src], bf16 out ---------------
__global__ __launch_bounds__(256) void gather1(
    const float* __restrict__ x, const int* __restrict__ rowptr,
    const int* __restrict__ eidx, unsigned short* __restrict__ agg, int nNodes)
{
    int n    = blockIdx.x * 4 + (threadIdx.x >> 6);
    int lane = threadIdx.x & 63;
    if (n >= nNodes) return;
    int beg = rowptr[n], end = rowptr[n + 1];
    float2 acc = *reinterpret_cast<const float2*>(x + (size_t)n * IN_F + lane * 2);
    for (int base = beg; base < end; base += 64) {
        int cnt = min(64, end - base);
        int e = (base + lane < end) ? eidx[base + lane] : 0;
        for (int i = 0; i < cnt; ++i) {
            int s = __shfl(e, i);
            float2 v = *reinterpret_cast<const float2*>(x + (size_t)s * IN_F + lane * 2);
            acc.x += v.x; acc.y += v.y;
        }
    }
    unsigned int p = (unsigned int)f2bf(acc.x) | ((unsigned int)f2bf(acc.y) << 16);
    *reinterpret_cast<unsigned int*>(agg + (size_t)n * IN_F + lane * 2) = p;
}

// ---- GEMM1 (MFMA): h1[M,256] = agg[M,128] @ W1, bf16 out ----------------
__global__ __launch_bounds__(256) void gemm1_mfma(
    const unsigned short* __restrict__ agg, const unsigned short* __restrict__ w1s,
    unsigned short* __restrict__ h1, int nNodes)
{
    int wave = threadIdx.x >> 6, lane = threadIdx.x & 63;
    int m0 = blockIdx.x * 64 + wave * 16;
    if (m0 >= nNodes) return;
    int row = lane & 15, quad = lane >> 4;
    f32x4 acc[16] = {};
    const bf16x8* aBase = reinterpret_cast<const bf16x8*>(
        agg + (size_t)(m0 + row) * IN_F + quad * 8);
    const bf16x8* bBase = reinterpret_cast<const bf16x8*>(w1s) + lane;
    #pragma unroll
    for (int ks = 0; ks < 4; ++ks) {
        bf16x8 a = aBase[ks * 4];
        #pragma unroll
        for (int nt = 0; nt < 16; ++nt) {
            bf16x8 b = bBase[(nt * 4 + ks) * 64];
            acc[nt] = __builtin_amdgcn_mfma_f32_16x16x32_bf16(a, b, acc[nt], 0, 0, 0);
        }
    }
    size_t outBase = (size_t)(m0 + quad * 4) * HID_F + row;
    #pragma unroll
    for (int nt = 0; nt < 16; ++nt)
        #pragma unroll
        for (int i = 0; i < 4; ++i)
            h1[outBase + (size_t)i * HID_F + nt * 16] = f2bf(acc[nt][i]);
}

// ---- GEMM2 (MFMA): z[M,64] = h1[M,256] @ W2, bf16 out -------------------
__global__ __launch_bounds__(256) void gemm2_mfma(
    const unsigned short* __restrict__ h1, const unsigned short* __restrict__ w2s,
    unsigned short* __restrict__ z, int nNodes)
{
    int wave = threadIdx.x >> 6, lane = threadIdx.x & 63;
    int m0 = blockIdx.x * 64 + wave * 16;
    if (m0 >= nNodes) return;
    int row = lane & 15, quad = lane >> 4;
    f32x4 acc[4] = {};
    const bf16x8* aBase = reinterpret_cast<const bf16x8*>(
        h1 + (size_t)(m0 + row) * HID_F + quad * 8);
    const bf16x8* bBase = reinterpret_cast<const bf16x8*>(w2s) + lane;
    #pragma unroll
    for (int ks = 0; ks < 8; ++ks) {
        bf16x8 a = aBase[ks * 4];
        #pragma unroll
        for (int nt = 0; nt < 4; ++nt) {
            bf16x8 b = bBase[(nt * 8 + ks) * 64];
            acc[nt] = __builtin_amdgcn_mfma_f32_16x16x32_bf16(a, b, acc[nt], 0, 0, 0);
        }
    }
    size_t outBase = (size_t)(m0 + quad * 4) * OUT_F + row;
    #pragma unroll
    for (int nt = 0; nt < 4; ++nt)
        #pragma unroll
        for (int i = 0; i < 4; ++i)
            z[outBase + (size_t)i * OUT_F + nt * 16] = f2bf(acc[nt][i]);
}

// ---- Layer-2 gather (commuted): out[n] = z[n] + sum z[src] --------------
__global__ __launch_bounds__(256) void gather2(
    const unsigned short* __restrict__ z, const int* __restrict__ rowptr,
    const int* __restrict__ eidx, float* __restrict__ out, int nNodes)
{
    int n    = blockIdx.x * 4 + (threadIdx.x >> 6);
    int lane = threadIdx.x & 63;
    if (n >= nNodes) return;
    int beg = rowptr[n], end = rowptr[n + 1];
    float acc = bf2f(z[(size_t)n * OUT_F + lane]);
    for (int base = beg; base < end; base += 64) {
        int cnt = min(64, end - base);
        int e = (base + lane < end) ? eidx[base + lane] : 0;
        for (int i = 0; i < cnt; ++i) {
            int s = __shfl(e, i);
            acc += bf2f(z[(size_t)s * OUT_F + lane]);
        }
    }
    out[(size_t)n * OUT_F + lane] = acc;
}

extern "C" void kernel_launch(void* const* d_in, const int* in_sizes, int n_in,
                              void* d_out, int out_size, void* d_ws, size_t ws_size,
                              hipStream_t stream) {
    const float* x  = (const float*)d_in[0];
    const int* esrc = (const int*)d_in[1];
    const int* edst = (const int*)d_in[2];
    const float* W1 = (const float*)d_in[3];
    const float* W2 = (const float*)d_in[4];
    float* out      = (float*)d_out;

    const int nNodes = in_sizes[0] / IN_F;
    const int nEdges = in_sizes[1];

    // Workspace (~85 MB; 102.4 MB known-safe):
    char* ws = (char*)d_ws;
    const size_t h1_b   = (size_t)nNodes * HID_F * sizeof(unsigned short);
    const size_t aggz_b = (size_t)nNodes * IN_F * sizeof(unsigned short);
    const size_t eidx_b = (size_t)nEdges * sizeof(int);
    unsigned short* h1  = (unsigned short*)ws;
    unsigned short* agg = (unsigned short*)(ws + h1_b);
    unsigned short* z   = (unsigned short*)(ws + h1_b);          // alias of agg
    int* eidx           = (int*)(ws + h1_b + aggz_b);
    unsigned short* w1s = (unsigned short*)(ws + h1_b + aggz_b + eidx_b);
    unsigned short* w2s = w1s + IN_F * HID_F;
    int* rowptr = (int*)(w2s + HID_F * OUT_F);
    int* cursor = rowptr + (nNodes + 1);
    int* deg    = cursor + nNodes;
    const int nbScan = (nNodes + SCAN_B - 1) / SCAN_B;
    int* bsum   = deg + nNodes;

    hipMemsetAsync(deg, 0, (size_t)nNodes * sizeof(int), stream);

    k_wconv<<<(IN_F * HID_F + 255) / 256, 256, 0, stream>>>(W1, W2, w1s, w2s);

    const int eBlocks = (nEdges + 255) / 256;
    k_deg<<<eBlocks, 256, 0, stream>>>(edst, deg, nEdges);
    k_bsum<<<nbScan, 256, 0, stream>>>(deg, bsum, nNodes);
    k_scanb<<<1, 256, 0, stream>>>(bsum, rowptr, nbScan, nNodes, nEdges);
    k_emit<<<nbScan, 256, 0, stream>>>(deg, bsum, rowptr, cursor, nNodes);
    k_place<<<eBlocks, 256, 0, stream>>>(esrc, edst, cursor, eidx, nEdges);

    const int nBlocks = (nNodes + 3) / 4;
    const int mBlocks = (nNodes + 63) / 64;
    gather1<<<nBlocks, 256, 0, stream>>>(x, rowptr, eidx, agg, nNodes);
    gemm1_mfma<<<mBlocks, 256, 0, stream>>>(agg, w1s, h1, nNodes);
    gemm2_mfma<<<mBlocks, 256, 0, stream>>>(h1, w2s, z, nNodes);
    gather2<<<nBlocks, 256, 0, stream>>>(z, rowptr, eidx, out, nNodes);
}

// Round 7
// 474.855 us; speedup vs baseline: 10.0012x; 1.2221x over previous
//
#include <hip/hip_runtime.h>
#include <hip/hip_bf16.h>

#define IN_F  128
#define HID_F 256
#define OUT_F 64
#define SCAN_B 512   // deg elements per scan block (2 per thread, 256 threads)

typedef __attribute__((ext_vector_type(8))) short bf16x8;
typedef __attribute__((ext_vector_type(4))) float f32x4;

__device__ __forceinline__ float bf2f(unsigned short u) {
    union { unsigned int i; float f; } v; v.i = ((unsigned int)u) << 16; return v.f;
}
__device__ __forceinline__ float bf2f_lo(unsigned int p) {
    union { unsigned int i; float f; } v; v.i = p << 16; return v.f;
}
__device__ __forceinline__ float bf2f_hi(unsigned int p) {
    union { unsigned int i; float f; } v; v.i = p & 0xffff0000u; return v.f;
}
__device__ __forceinline__ unsigned short f2bf(float f) {
    __hip_bfloat16 b = __float2bfloat16(f);
    return *reinterpret_cast<unsigned short*>(&b);
}

// ---- x fp32 -> bf16 (8 elems/thread) ------------------------------------
__global__ __launch_bounds__(256) void k_xconv(
    const float* __restrict__ x, unsigned short* __restrict__ xb, long long total8)
{
    long long i = (long long)blockIdx.x * blockDim.x + threadIdx.x;
    if (i >= total8) return;
    const float4* p = reinterpret_cast<const float4*>(x) + i * 2;
    float4 a = p[0], b = p[1];
    ushort4 o0, o1;
    o0.x = f2bf(a.x); o0.y = f2bf(a.y); o0.z = f2bf(a.z); o0.w = f2bf(a.w);
    o1.x = f2bf(b.x); o1.y = f2bf(b.y); o1.z = f2bf(b.z); o1.w = f2bf(b.w);
    reinterpret_cast<ushort4*>(xb)[i * 2]     = o0;
    reinterpret_cast<ushort4*>(xb)[i * 2 + 1] = o1;
}

// ---- CSR build ----------------------------------------------------------
__global__ __launch_bounds__(256) void k_deg(
    const int* __restrict__ dst, int* __restrict__ deg, int nEdges)
{
    int e = blockIdx.x * blockDim.x + threadIdx.x;
    if (e < nEdges) atomicAdd(&deg[dst[e]], 1);
}

__global__ __launch_bounds__(256) void k_bsum(
    const int* __restrict__ deg, int* __restrict__ bsum, int nNodes)
{
    __shared__ int sh[256];
    int t = threadIdx.x;
    int i0 = blockIdx.x * SCAN_B + 2 * t, i1 = i0 + 1;
    int s = ((i0 < nNodes) ? deg[i0] : 0) + ((i1 < nNodes) ? deg[i1] : 0);
    sh[t] = s; __syncthreads();
    for (int d = 128; d > 0; d >>= 1) {
        if (t < d) sh[t] += sh[t + d];
        __syncthreads();
    }
    if (t == 0) bsum[blockIdx.x] = sh[0];
}

__global__ __launch_bounds__(256) void k_scanb(
    int* __restrict__ bsum, int* __restrict__ rowptr, int nb, int nNodes, int nEdges)
{
    __shared__ int sh[256];
    int t = threadIdx.x;
    int carry = 0;
    for (int base = 0; base < nb; base += 256) {
        int v = (base + t < nb) ? bsum[base + t] : 0;
        sh[t] = v; __syncthreads();
        for (int d = 1; d < 256; d <<= 1) {
            int add = (t >= d) ? sh[t - d] : 0;
            __syncthreads();
            sh[t] += add;
            __syncthreads();
        }
        if (base + t < nb) bsum[base + t] = carry + sh[t] - v;
        carry += sh[255];
        __syncthreads();
    }
    if (t == 0) rowptr[nNodes] = nEdges;
}

__global__ __launch_bounds__(256) void k_emit(
    const int* __restrict__ deg, const int* __restrict__ bsum,
    int* __restrict__ rowptr, int* __restrict__ cursor, int nNodes)
{
    __shared__ int sh[256];
    int t = threadIdx.x;
    int i0 = blockIdx.x * SCAN_B + 2 * t, i1 = i0 + 1;
    int d0 = (i0 < nNodes) ? deg[i0] : 0;
    int d1 = (i1 < nNodes) ? deg[i1] : 0;
    int s = d0 + d1;
    sh[t] = s; __syncthreads();
    for (int d = 1; d < 256; d <<= 1) {
        int add = (t >= d) ? sh[t - d] : 0;
        __syncthreads();
        sh[t] += add;
        __syncthreads();
    }
    int excl = bsum[blockIdx.x] + sh[t] - s;
    if (i0 < nNodes) { rowptr[i0] = excl;      cursor[i0] = excl; }
    if (i1 < nNodes) { rowptr[i1] = excl + d0; cursor[i1] = excl + d0; }
}

__global__ __launch_bounds__(256) void k_place(
    const int* __restrict__ src, const int* __restrict__ dst,
    int* __restrict__ cursor, int* __restrict__ eidx, int nEdges)
{
    int e = blockIdx.x * blockDim.x + threadIdx.x;
    if (e < nEdges) {
        int j = atomicAdd(&cursor[dst[e]], 1);
        eidx[j] = src[e];
    }
}

// ---- Weight swizzle: fp32 W -> bf16 in B-fragment order -----------------
__global__ __launch_bounds__(256) void k_wconv(
    const float* __restrict__ W1, const float* __restrict__ W2,
    unsigned short* __restrict__ w1s, unsigned short* __restrict__ w2s)
{
    int idx = blockIdx.x * blockDim.x + threadIdx.x;
    if (idx < IN_F * HID_F) {            // W1: 16 ntiles x 4 ksteps
        int c = idx >> 9, L = (idx >> 3) & 63, j = idx & 7;
        int ntile = c >> 2, kstep = c & 3;
        int k = kstep * 32 + (L >> 4) * 8 + j;
        int n = ntile * 16 + (L & 15);
        w1s[idx] = f2bf(W1[k * HID_F + n]);
    }
    if (idx < HID_F * OUT_F) {           // W2: 4 ntiles x 8 ksteps
        int c = idx >> 9, L = (idx >> 3) & 63, j = idx & 7;
        int ntile = c >> 3, kstep = c & 7;
        int k = kstep * 32 + (L >> 4) * 8 + j;
        int n = ntile * 16 + (L & 15);
        w2s[idx] = f2bf(W2[k * OUT_F + n]);
    }
}

// ---- Layer-1 gather: agg[n] = xb[n] + sum xb[src], bf16 in/out ----------
// One wave per node; lane holds features {2*lane, 2*lane+1}; 4-edge MLP unroll.
__global__ __launch_bounds__(256) void gather1(
    const unsigned short* __restrict__ xb, const int* __restrict__ rowptr,
    const int* __restrict__ eidx, unsigned short* __restrict__ agg, int nNodes)
{
    int n    = blockIdx.x * 4 + (threadIdx.x >> 6);
    int lane = threadIdx.x & 63;
    if (n >= nNodes) return;
    int beg = rowptr[n], end = rowptr[n + 1];
    unsigned int self = *reinterpret_cast<const unsigned int*>(
        xb + (size_t)n * IN_F + lane * 2);
    float ax = bf2f_lo(self), ay = bf2f_hi(self);
    for (int base = beg; base < end; base += 64) {
        int cnt = min(64, end - base);
        int e = (base + lane < end) ? eidx[base + lane] : 0;
        int i = 0;
        for (; i + 4 <= cnt; i += 4) {
            int s0 = __shfl(e, i), s1 = __shfl(e, i + 1);
            int s2 = __shfl(e, i + 2), s3 = __shfl(e, i + 3);
            unsigned int v0 = *reinterpret_cast<const unsigned int*>(xb + (size_t)s0 * IN_F + lane * 2);
            unsigned int v1 = *reinterpret_cast<const unsigned int*>(xb + (size_t)s1 * IN_F + lane * 2);
            unsigned int v2 = *reinterpret_cast<const unsigned int*>(xb + (size_t)s2 * IN_F + lane * 2);
            unsigned int v3 = *reinterpret_cast<const unsigned int*>(xb + (size_t)s3 * IN_F + lane * 2);
            ax += bf2f_lo(v0) + bf2f_lo(v1) + bf2f_lo(v2) + bf2f_lo(v3);
            ay += bf2f_hi(v0) + bf2f_hi(v1) + bf2f_hi(v2) + bf2f_hi(v3);
        }
        for (; i < cnt; ++i) {
            int s = __shfl(e, i);
            unsigned int v = *reinterpret_cast<const unsigned int*>(xb + (size_t)s * IN_F + lane * 2);
            ax += bf2f_lo(v); ay += bf2f_hi(v);
        }
    }
    unsigned int p = (unsigned int)f2bf(ax) | ((unsigned int)f2bf(ay) << 16);
    *reinterpret_cast<unsigned int*>(agg + (size_t)n * IN_F + lane * 2) = p;
}

// ---- GEMM1 (MFMA): h1[M,256] = agg[M,128] @ W1, bf16 out ----------------
__global__ __launch_bounds__(256) void gemm1_mfma(
    const unsigned short* __restrict__ agg, const unsigned short* __restrict__ w1s,
    unsigned short* __restrict__ h1, int nNodes)
{
    int wave = threadIdx.x >> 6, lane = threadIdx.x & 63;
    int m0 = blockIdx.x * 64 + wave * 16;
    if (m0 >= nNodes) return;
    int row = lane & 15, quad = lane >> 4;
    f32x4 acc[16] = {};
    const bf16x8* aBase = reinterpret_cast<const bf16x8*>(
        agg + (size_t)(m0 + row) * IN_F + quad * 8);
    const bf16x8* bBase = reinterpret_cast<const bf16x8*>(w1s) + lane;
    #pragma unroll
    for (int ks = 0; ks < 4; ++ks) {
        bf16x8 a = aBase[ks * 4];
        #pragma unroll
        for (int nt = 0; nt < 16; ++nt) {
            bf16x8 b = bBase[(nt * 4 + ks) * 64];
            acc[nt] = __builtin_amdgcn_mfma_f32_16x16x32_bf16(a, b, acc[nt], 0, 0, 0);
        }
    }
    size_t outBase = (size_t)(m0 + quad * 4) * HID_F + row;
    #pragma unroll
    for (int nt = 0; nt < 16; ++nt)
        #pragma unroll
        for (int i = 0; i < 4; ++i)
            h1[outBase + (size_t)i * HID_F + nt * 16] = f2bf(acc[nt][i]);
}

// ---- GEMM2 (MFMA): z[M,64] = h1[M,256] @ W2, bf16 out -------------------
__global__ __launch_bounds__(256) void gemm2_mfma(
    const unsigned short* __restrict__ h1, const unsigned short* __restrict__ w2s,
    unsigned short* __restrict__ z, int nNodes)
{
    int wave = threadIdx.x >> 6, lane = threadIdx.x & 63;
    int m0 = blockIdx.x * 64 + wave * 16;
    if (m0 >= nNodes) return;
    int row = lane & 15, quad = lane >> 4;
    f32x4 acc[4] = {};
    const bf16x8* aBase = reinterpret_cast<const bf16x8*>(
        h1 + (size_t)(m0 + row) * HID_F + quad * 8);
    const bf16x8* bBase = reinterpret_cast<const bf16x8*>(w2s) + lane;
    #pragma unroll
    for (int ks = 0; ks < 8; ++ks) {
        bf16x8 a = aBase[ks * 4];
        #pragma unroll
        for (int nt = 0; nt < 4; ++nt) {
            bf16x8 b = bBase[(nt * 8 + ks) * 64];
            acc[nt] = __builtin_amdgcn_mfma_f32_16x16x32_bf16(a, b, acc[nt], 0, 0, 0);
        }
    }
    size_t outBase = (size_t)(m0 + quad * 4) * OUT_F + row;
    #pragma unroll
    for (int nt = 0; nt < 4; ++nt)
        #pragma unroll
        for (int i = 0; i < 4; ++i)
            z[outBase + (size_t)i * OUT_F + nt * 16] = f2bf(acc[nt][i]);
}

// ---- Layer-2 gather (commuted): out[n] = z[n] + sum z[src], 4-way MLP ---
__global__ __launch_bounds__(256) void gather2(
    const unsigned short* __restrict__ z, const int* __restrict__ rowptr,
    const int* __restrict__ eidx, float* __restrict__ out, int nNodes)
{
    int n    = blockIdx.x * 4 + (threadIdx.x >> 6);
    int lane = threadIdx.x & 63;
    if (n >= nNodes) return;
    int beg = rowptr[n], end = rowptr[n + 1];
    float acc = bf2f(z[(size_t)n * OUT_F + lane]);
    for (int base = beg; base < end; base += 64) {
        int cnt = min(64, end - base);
        int e = (base + lane < end) ? eidx[base + lane] : 0;
        int i = 0;
        for (; i + 4 <= cnt; i += 4) {
            int s0 = __shfl(e, i), s1 = __shfl(e, i + 1);
            int s2 = __shfl(e, i + 2), s3 = __shfl(e, i + 3);
            unsigned short v0 = z[(size_t)s0 * OUT_F + lane];
            unsigned short v1 = z[(size_t)s1 * OUT_F + lane];
            unsigned short v2 = z[(size_t)s2 * OUT_F + lane];
            unsigned short v3 = z[(size_t)s3 * OUT_F + lane];
            acc += bf2f(v0) + bf2f(v1) + bf2f(v2) + bf2f(v3);
        }
        for (; i < cnt; ++i) {
            int s = __shfl(e, i);
            acc += bf2f(z[(size_t)s * OUT_F + lane]);
        }
    }
    out[(size_t)n * OUT_F + lane] = acc;
}

extern "C" void kernel_launch(void* const* d_in, const int* in_sizes, int n_in,
                              void* d_out, int out_size, void* d_ws, size_t ws_size,
                              hipStream_t stream) {
    const float* x  = (const float*)d_in[0];
    const int* esrc = (const int*)d_in[1];
    const int* edst = (const int*)d_in[2];
    const float* W1 = (const float*)d_in[3];
    const float* W2 = (const float*)d_in[4];
    float* out      = (float*)d_out;

    const int nNodes = in_sizes[0] / IN_F;
    const int nEdges = in_sizes[1];

    // Workspace (~85 MB; 102.4 MB known-safe). xb aliases h1 (dead until gemm1).
    char* ws = (char*)d_ws;
    const size_t h1_b   = (size_t)nNodes * HID_F * sizeof(unsigned short);
    const size_t aggz_b = (size_t)nNodes * IN_F * sizeof(unsigned short);
    const size_t eidx_b = (size_t)nEdges * sizeof(int);
    unsigned short* h1  = (unsigned short*)ws;
    unsigned short* xb  = (unsigned short*)ws;                   // alias of h1
    unsigned short* agg = (unsigned short*)(ws + h1_b);
    unsigned short* z   = (unsigned short*)(ws + h1_b);          // alias of agg
    int* eidx           = (int*)(ws + h1_b + aggz_b);
    unsigned short* w1s = (unsigned short*)(ws + h1_b + aggz_b + eidx_b);
    unsigned short* w2s = w1s + IN_F * HID_F;
    int* rowptr = (int*)(w2s + HID_F * OUT_F);
    int* cursor = rowptr + (nNodes + 1);
    int* deg    = cursor + nNodes;
    const int nbScan = (nNodes + SCAN_B - 1) / SCAN_B;
    int* bsum   = deg + nNodes;

    hipMemsetAsync(deg, 0, (size_t)nNodes * sizeof(int), stream);

    k_wconv<<<(IN_F * HID_F + 255) / 256, 256, 0, stream>>>(W1, W2, w1s, w2s);

    long long total8 = (long long)nNodes * IN_F / 8;
    k_xconv<<<(int)((total8 + 255) / 256), 256, 0, stream>>>(x, xb, total8);

    const int eBlocks = (nEdges + 255) / 256;
    k_deg<<<eBlocks, 256, 0, stream>>>(edst, deg, nEdges);
    k_bsum<<<nbScan, 256, 0, stream>>>(deg, bsum, nNodes);
    k_scanb<<<1, 256, 0, stream>>>(bsum, rowptr, nbScan, nNodes, nEdges);
    k_emit<<<nbScan, 256, 0, stream>>>(deg, bsum, rowptr, cursor, nNodes);
    k_place<<<eBlocks, 256, 0, stream>>>(esrc, edst, cursor, eidx, nEdges);

    const int nBlocks = (nNodes + 3) / 4;
    const int mBlocks = (nNodes + 63) / 64;
    gather1<<<nBlocks, 256, 0, stream>>>(xb, rowptr, eidx, agg, nNodes);
    gemm1_mfma<<<mBlocks, 256, 0, stream>>>(agg, w1s, h1, nNodes);
    gemm2_mfma<<<mBlocks, 256, 0, stream>>>(h1, w2s, z, nNodes);
    gather2<<<nBlocks, 256, 0, stream>>>(z, rowptr, eidx, out, nNodes);
}

// Round 8
// 402.329 us; speedup vs baseline: 11.8041x; 1.1803x over previous
//
#include <hip/hip_runtime.h>
#include <hip/hip_bf16.h>

#define IN_F  128
#define HID_F 256
#define OUT_F 64
#define BUCKET_SHIFT 9
#define BUCKET_SZ 512
#define EPB 8192            // edges per binning block

typedef __attribute__((ext_vector_type(8))) short bf16x8;
typedef __attribute__((ext_vector_type(4))) float f32x4;

__device__ __forceinline__ float bf2f(unsigned short u) {
    union { unsigned int i; float f; } v; v.i = ((unsigned int)u) << 16; return v.f;
}
__device__ __forceinline__ float bf2f_lo(unsigned int p) {
    union { unsigned int i; float f; } v; v.i = p << 16; return v.f;
}
__device__ __forceinline__ float bf2f_hi(unsigned int p) {
    union { unsigned int i; float f; } v; v.i = p & 0xffff0000u; return v.f;
}
__device__ __forceinline__ unsigned short f2bf(float f) {
    __hip_bfloat16 b = __float2bfloat16(f);
    return *reinterpret_cast<unsigned short*>(&b);
}

// ---- x fp32 -> bf16 (8 elems/thread) ------------------------------------
__global__ __launch_bounds__(256) void k_xconv(
    const float* __restrict__ x, unsigned short* __restrict__ xb, long long total8)
{
    long long i = (long long)blockIdx.x * blockDim.x + threadIdx.x;
    if (i >= total8) return;
    const float4* p = reinterpret_cast<const float4*>(x) + i * 2;
    float4 a = p[0], b = p[1];
    ushort4 o0, o1;
    o0.x = f2bf(a.x); o0.y = f2bf(a.y); o0.z = f2bf(a.z); o0.w = f2bf(a.w);
    o1.x = f2bf(b.x); o1.y = f2bf(b.y); o1.z = f2bf(b.z); o1.w = f2bf(b.w);
    reinterpret_cast<ushort4*>(xb)[i * 2]     = o0;
    reinterpret_cast<ushort4*>(xb)[i * 2 + 1] = o1;
}

// ---- CSR build via bucketed multisplit (no global per-edge atomics) -----
// Phase 1: per-(block) LDS histogram over buckets -> counts[b*A + i]
__global__ __launch_bounds__(256) void k_hist(
    const int* __restrict__ dst, int* __restrict__ counts,
    int nEdges, int NB)
{
    __shared__ int hist[256];
    int t = threadIdx.x;
    hist[t] = 0;
    __syncthreads();
    long long base = (long long)blockIdx.x * EPB;
    #pragma unroll
    for (int k = 0; k < EPB / 256; ++k) {
        long long e = base + k * 256 + t;
        if (e < nEdges) atomicAdd(&hist[dst[e] >> BUCKET_SHIFT], 1);
    }
    __syncthreads();
    if (t < NB) counts[t * gridDim.x + blockIdx.x] = hist[t];
}

// Phase 2: one block. Bucket totals -> exclusive bases; counts -> start cursors.
__global__ __launch_bounds__(256) void k_bucketscan(
    int* __restrict__ counts, int* __restrict__ bucketBase,
    int* __restrict__ rowptr, int A, int NB, int nNodes, int nEdges)
{
    __shared__ int tot[256];
    int t = threadIdx.x;
    int sum = 0;
    if (t < NB)
        for (int i = 0; i < A; ++i) sum += counts[t * A + i];
    tot[t] = sum;
    __syncthreads();
    for (int d = 1; d < 256; d <<= 1) {
        int add = (t >= d) ? tot[t - d] : 0;
        __syncthreads();
        tot[t] += add;
        __syncthreads();
    }
    int base = tot[t] - sum;           // exclusive
    if (t < NB) {
        bucketBase[t] = base;
        int run = base;
        for (int i = 0; i < A; ++i) {
            int c = counts[t * A + i];
            counts[t * A + i] = run;
            run += c;
        }
    }
    if (t == 0) { bucketBase[NB] = nEdges; rowptr[nNodes] = nEdges; }
}

// Phase 3: place (src,dst) pairs into bucket-contiguous binned[] (8B stores).
__global__ __launch_bounds__(256) void k_bin(
    const int* __restrict__ src, const int* __restrict__ dst,
    const int* __restrict__ counts, unsigned long long* __restrict__ binned,
    int nEdges, int NB)
{
    __shared__ int cur[256];
    int t = threadIdx.x;
    if (t < NB) cur[t] = counts[t * gridDim.x + blockIdx.x];
    __syncthreads();
    long long base = (long long)blockIdx.x * EPB;
    #pragma unroll
    for (int k = 0; k < EPB / 256; ++k) {
        long long e = base + k * 256 + t;
        if (e < nEdges) {
            int s = src[e], d = dst[e];
            int pos = atomicAdd(&cur[d >> BUCKET_SHIFT], 1);
            binned[pos] = (((unsigned long long)(unsigned)d) << 32) | (unsigned)s;
        }
    }
}

// Phase 4: per-bucket local CSR: LDS deg hist -> LDS scan -> rowptr + eidx.
__global__ __launch_bounds__(256) void k_localcsr(
    const unsigned long long* __restrict__ binned, const int* __restrict__ bucketBase,
    int* __restrict__ rowptr, int* __restrict__ eidx, int nNodes)
{
    __shared__ int ldeg[BUCKET_SZ];
    __shared__ int lscan[256];
    int t = threadIdx.x;
    ldeg[t] = 0; ldeg[t + 256] = 0;
    __syncthreads();
    int eb0 = bucketBase[blockIdx.x], eb1 = bucketBase[blockIdx.x + 1];
    int node0 = blockIdx.x << BUCKET_SHIFT;
    for (int e = eb0 + t; e < eb1; e += 256) {
        int d = (int)(binned[e] >> 32);
        atomicAdd(&ldeg[d - node0], 1);
    }
    __syncthreads();
    int d0 = ldeg[2 * t], d1 = ldeg[2 * t + 1];
    int s = d0 + d1;
    lscan[t] = s;
    __syncthreads();
    for (int d = 1; d < 256; d <<= 1) {
        int add = (t >= d) ? lscan[t - d] : 0;
        __syncthreads();
        lscan[t] += add;
        __syncthreads();
    }
    int excl = lscan[t] - s;
    ldeg[2 * t]     = excl;        // becomes local cursor
    ldeg[2 * t + 1] = excl + d0;
    int n0 = node0 + 2 * t;
    if (n0 < nNodes)     rowptr[n0]     = eb0 + excl;
    if (n0 + 1 < nNodes) rowptr[n0 + 1] = eb0 + excl + d0;
    __syncthreads();
    for (int e = eb0 + t; e < eb1; e += 256) {
        unsigned long long p = binned[e];
        int d = (int)(p >> 32), sv = (int)(p & 0xffffffffu);
        int pos = atomicAdd(&ldeg[d - node0], 1);
        eidx[eb0 + pos] = sv;
    }
}

// ---- Weight swizzle: fp32 W -> bf16 in B-fragment order -----------------
__global__ __launch_bounds__(256) void k_wconv(
    const float* __restrict__ W1, const float* __restrict__ W2,
    unsigned short* __restrict__ w1s, unsigned short* __restrict__ w2s)
{
    int idx = blockIdx.x * blockDim.x + threadIdx.x;
    if (idx < IN_F * HID_F) {            // W1: 16 ntiles x 4 ksteps
        int c = idx >> 9, L = (idx >> 3) & 63, j = idx & 7;
        int ntile = c >> 2, kstep = c & 3;
        int k = kstep * 32 + (L >> 4) * 8 + j;
        int n = ntile * 16 + (L & 15);
        w1s[idx] = f2bf(W1[k * HID_F + n]);
    }
    if (idx < HID_F * OUT_F) {           // W2: 4 ntiles x 8 ksteps
        int c = idx >> 9, L = (idx >> 3) & 63, j = idx & 7;
        int ntile = c >> 3, kstep = c & 7;
        int k = kstep * 32 + (L >> 4) * 8 + j;
        int n = ntile * 16 + (L & 15);
        w2s[idx] = f2bf(W2[k * OUT_F + n]);
    }
}

// ---- Layer-1 gather: agg[n] = xb[n] + sum xb[src] -----------------------
__global__ __launch_bounds__(256) void gather1(
    const unsigned short* __restrict__ xb, const int* __restrict__ rowptr,
    const int* __restrict__ eidx, unsigned short* __restrict__ agg, int nNodes)
{
    int n    = blockIdx.x * 4 + (threadIdx.x >> 6);
    int lane = threadIdx.x & 63;
    if (n >= nNodes) return;
    int beg = rowptr[n], end = rowptr[n + 1];
    unsigned int self = *reinterpret_cast<const unsigned int*>(
        xb + (size_t)n * IN_F + lane * 2);
    float ax = bf2f_lo(self), ay = bf2f_hi(self);
    for (int base = beg; base < end; base += 64) {
        int cnt = min(64, end - base);
        int e = (base + lane < end) ? eidx[base + lane] : 0;
        int i = 0;
        for (; i + 4 <= cnt; i += 4) {
            int s0 = __shfl(e, i), s1 = __shfl(e, i + 1);
            int s2 = __shfl(e, i + 2), s3 = __shfl(e, i + 3);
            unsigned int v0 = *reinterpret_cast<const unsigned int*>(xb + (size_t)s0 * IN_F + lane * 2);
            unsigned int v1 = *reinterpret_cast<const unsigned int*>(xb + (size_t)s1 * IN_F + lane * 2);
            unsigned int v2 = *reinterpret_cast<const unsigned int*>(xb + (size_t)s2 * IN_F + lane * 2);
            unsigned int v3 = *reinterpret_cast<const unsigned int*>(xb + (size_t)s3 * IN_F + lane * 2);
            ax += bf2f_lo(v0) + bf2f_lo(v1) + bf2f_lo(v2) + bf2f_lo(v3);
            ay += bf2f_hi(v0) + bf2f_hi(v1) + bf2f_hi(v2) + bf2f_hi(v3);
        }
        for (; i < cnt; ++i) {
            int s = __shfl(e, i);
            unsigned int v = *reinterpret_cast<const unsigned int*>(xb + (size_t)s * IN_F + lane * 2);
            ax += bf2f_lo(v); ay += bf2f_hi(v);
        }
    }
    unsigned int p = (unsigned int)f2bf(ax) | ((unsigned int)f2bf(ay) << 16);
    *reinterpret_cast<unsigned int*>(agg + (size_t)n * IN_F + lane * 2) = p;
}

// ---- GEMM1 (MFMA): h1[M,256] = agg[M,128] @ W1, bf16 out ----------------
__global__ __launch_bounds__(256) void gemm1_mfma(
    const unsigned short* __restrict__ agg, const unsigned short* __restrict__ w1s,
    unsigned short* __restrict__ h1, int nNodes)
{
    int wave = threadIdx.x >> 6, lane = threadIdx.x & 63;
    int m0 = blockIdx.x * 64 + wave * 16;
    if (m0 >= nNodes) return;
    int row = lane & 15, quad = lane >> 4;
    f32x4 acc[16] = {};
    const bf16x8* aBase = reinterpret_cast<const bf16x8*>(
        agg + (size_t)(m0 + row) * IN_F + quad * 8);
    const bf16x8* bBase = reinterpret_cast<const bf16x8*>(w1s) + lane;
    #pragma unroll
    for (int ks = 0; ks < 4; ++ks) {
        bf16x8 a = aBase[ks * 4];
        #pragma unroll
        for (int nt = 0; nt < 16; ++nt) {
            bf16x8 b = bBase[(nt * 4 + ks) * 64];
            acc[nt] = __builtin_amdgcn_mfma_f32_16x16x32_bf16(a, b, acc[nt], 0, 0, 0);
        }
    }
    size_t outBase = (size_t)(m0 + quad * 4) * HID_F + row;
    #pragma unroll
    for (int i = 0; i < 4; ++i) {
        if (m0 + quad * 4 + i >= nNodes) break;   // tail guard: don't write past h1
        #pragma unroll
        for (int nt = 0; nt < 16; ++nt)
            h1[outBase + (size_t)i * HID_F + nt * 16] = f2bf(acc[nt][i]);
    }
}

// ---- GEMM2 (MFMA): z[M,64] = h1[M,256] @ W2, bf16 out -------------------
__global__ __launch_bounds__(256) void gemm2_mfma(
    const unsigned short* __restrict__ h1, const unsigned short* __restrict__ w2s,
    unsigned short* __restrict__ z, int nNodes)
{
    int wave = threadIdx.x >> 6, lane = threadIdx.x & 63;
    int m0 = blockIdx.x * 64 + wave * 16;
    if (m0 >= nNodes) return;
    int row = lane & 15, quad = lane >> 4;
    f32x4 acc[4] = {};
    const bf16x8* aBase = reinterpret_cast<const bf16x8*>(
        h1 + (size_t)(m0 + row) * HID_F + quad * 8);
    const bf16x8* bBase = reinterpret_cast<const bf16x8*>(w2s) + lane;
    #pragma unroll
    for (int ks = 0; ks < 8; ++ks) {
        bf16x8 a = aBase[ks * 4];
        #pragma unroll
        for (int nt = 0; nt < 4; ++nt) {
            bf16x8 b = bBase[(nt * 8 + ks) * 64];
            acc[nt] = __builtin_amdgcn_mfma_f32_16x16x32_bf16(a, b, acc[nt], 0, 0, 0);
        }
    }
    size_t outBase = (size_t)(m0 + quad * 4) * OUT_F + row;
    #pragma unroll
    for (int i = 0; i < 4; ++i) {
        if (m0 + quad * 4 + i >= nNodes) break;   // tail guard
        #pragma unroll
        for (int nt = 0; nt < 4; ++nt)
            z[outBase + (size_t)i * OUT_F + nt * 16] = f2bf(acc[nt][i]);
    }
}

// ---- Layer-2 gather (commuted): out[n] = z[n] + sum z[src] --------------
__global__ __launch_bounds__(256) void gather2(
    const unsigned short* __restrict__ z, const int* __restrict__ rowptr,
    const int* __restrict__ eidx, float* __restrict__ out, int nNodes)
{
    int n    = blockIdx.x * 4 + (threadIdx.x >> 6);
    int lane = threadIdx.x & 63;
    if (n >= nNodes) return;
    int beg = rowptr[n], end = rowptr[n + 1];
    float acc = bf2f(z[(size_t)n * OUT_F + lane]);
    for (int base = beg; base < end; base += 64) {
        int cnt = min(64, end - base);
        int e = (base + lane < end) ? eidx[base + lane] : 0;
        int i = 0;
        for (; i + 4 <= cnt; i += 4) {
            int s0 = __shfl(e, i), s1 = __shfl(e, i + 1);
            int s2 = __shfl(e, i + 2), s3 = __shfl(e, i + 3);
            unsigned short v0 = z[(size_t)s0 * OUT_F + lane];
            unsigned short v1 = z[(size_t)s1 * OUT_F + lane];
            unsigned short v2 = z[(size_t)s2 * OUT_F + lane];
            unsigned short v3 = z[(size_t)s3 * OUT_F + lane];
            acc += bf2f(v0) + bf2f(v1) + bf2f(v2) + bf2f(v3);
        }
        for (; i < cnt; ++i) {
            int s = __shfl(e, i);
            acc += bf2f(z[(size_t)s * OUT_F + lane]);
        }
    }
    out[(size_t)n * OUT_F + lane] = acc;
}

extern "C" void kernel_launch(void* const* d_in, const int* in_sizes, int n_in,
                              void* d_out, int out_size, void* d_ws, size_t ws_size,
                              hipStream_t stream) {
    const float* x  = (const float*)d_in[0];
    const int* esrc = (const int*)d_in[1];
    const int* edst = (const int*)d_in[2];
    const float* W1 = (const float*)d_in[3];
    const float* W2 = (const float*)d_in[4];
    float* out      = (float*)d_out;

    const int nNodes = in_sizes[0] / IN_F;
    const int nEdges = in_sizes[1];
    const int NB = (nNodes + BUCKET_SZ - 1) / BUCKET_SZ;   // 196 (must be <= 256)
    const int A  = (nEdges + EPB - 1) / EPB;               // 196 binning blocks

    // Workspace (~96.7 MB; 110.4 MB known-safe from R3):
    //   h1/xb bf16 [N,256]  51.2 MB   (xb dead at gemm1-time)
    //   agg/z bf16          25.6 MB
    //   binned u64 [E]      12.8 MB
    //   eidx int[E]          6.4 MB
    //   w1s/w2s, rowptr, counts, bucketBase   ~0.7 MB
    char* ws = (char*)d_ws;
    const size_t h1_b     = (size_t)nNodes * HID_F * sizeof(unsigned short);
    const size_t aggz_b   = (size_t)nNodes * IN_F * sizeof(unsigned short);
    const size_t binned_b = (size_t)nEdges * sizeof(unsigned long long);
    const size_t eidx_b   = (size_t)nEdges * sizeof(int);
    unsigned short* h1  = (unsigned short*)ws;
    unsigned short* xb  = (unsigned short*)ws;                   // alias of h1
    unsigned short* agg = (unsigned short*)(ws + h1_b);
    unsigned short* z   = (unsigned short*)(ws + h1_b);          // alias of agg
    unsigned long long* binned = (unsigned long long*)(ws + h1_b + aggz_b);
    int* eidx           = (int*)(ws + h1_b + aggz_b + binned_b);
    unsigned short* w1s = (unsigned short*)(ws + h1_b + aggz_b + binned_b + eidx_b);
    unsigned short* w2s = w1s + IN_F * HID_F;
    int* rowptr     = (int*)(w2s + HID_F * OUT_F);
    int* counts     = rowptr + (nNodes + 1);
    int* bucketBase = counts + (size_t)NB * A;

    k_wconv<<<(IN_F * HID_F + 255) / 256, 256, 0, stream>>>(W1, W2, w1s, w2s);

    long long total8 = (long long)nNodes * IN_F / 8;
    k_xconv<<<(int)((total8 + 255) / 256), 256, 0, stream>>>(x, xb, total8);

    k_hist<<<A, 256, 0, stream>>>(edst, counts, nEdges, NB);
    k_bucketscan<<<1, 256, 0, stream>>>(counts, bucketBase, rowptr, A, NB, nNodes, nEdges);
    k_bin<<<A, 256, 0, stream>>>(esrc, edst, counts, binned, nEdges, NB);
    k_localcsr<<<NB, 256, 0, stream>>>(binned, bucketBase, rowptr, eidx, nNodes);

    const int nBlocks = (nNodes + 3) / 4;
    const int mBlocks = (nNodes + 63) / 64;
    gather1<<<nBlocks, 256, 0, stream>>>(xb, rowptr, eidx, agg, nNodes);
    gemm1_mfma<<<mBlocks, 256, 0, stream>>>(agg, w1s, h1, nNodes);
    gemm2_mfma<<<mBlocks, 256, 0, stream>>>(h1, w2s, z, nNodes);
    gather2<<<nBlocks, 256, 0, stream>>>(z, rowptr, eidx, out, nNodes);
}

// Round 9
// 343.391 us; speedup vs baseline: 13.8301x; 1.1716x over previous
//
#include <hip/hip_runtime.h>
#include <hip/hip_bf16.h>

#define IN_F  128
#define HID_F 256
#define OUT_F 64
#define BUCKET_SHIFT 9
#define BUCKET_SZ 512
#define EPB 8192            // edges per binning block

typedef __attribute__((ext_vector_type(8))) short bf16x8;
typedef __attribute__((ext_vector_type(4))) float f32x4;

__device__ __forceinline__ float bf2f(unsigned short u) {
    union { unsigned int i; float f; } v; v.i = ((unsigned int)u) << 16; return v.f;
}
__device__ __forceinline__ float bf2f_lo(unsigned int p) {
    union { unsigned int i; float f; } v; v.i = p << 16; return v.f;
}
__device__ __forceinline__ float bf2f_hi(unsigned int p) {
    union { unsigned int i; float f; } v; v.i = p & 0xffff0000u; return v.f;
}
__device__ __forceinline__ unsigned short f2bf(float f) {
    __hip_bfloat16 b = __float2bfloat16(f);
    return *reinterpret_cast<unsigned short*>(&b);
}

// ---- x fp32 -> bf16 (8 elems/thread) ------------------------------------
__global__ __launch_bounds__(256) void k_xconv(
    const float* __restrict__ x, unsigned short* __restrict__ xb, long long total8)
{
    long long i = (long long)blockIdx.x * blockDim.x + threadIdx.x;
    if (i >= total8) return;
    const float4* p = reinterpret_cast<const float4*>(x) + i * 2;
    float4 a = p[0], b = p[1];
    ushort4 o0, o1;
    o0.x = f2bf(a.x); o0.y = f2bf(a.y); o0.z = f2bf(a.z); o0.w = f2bf(a.w);
    o1.x = f2bf(b.x); o1.y = f2bf(b.y); o1.z = f2bf(b.z); o1.w = f2bf(b.w);
    reinterpret_cast<ushort4*>(xb)[i * 2]     = o0;
    reinterpret_cast<ushort4*>(xb)[i * 2 + 1] = o1;
}

// ---- CSR build via bucketed multisplit (no global per-edge atomics) -----
// Phase 1: per-block LDS histogram over buckets -> counts[b*A + i]
__global__ __launch_bounds__(256) void k_hist(
    const int* __restrict__ dst, int* __restrict__ counts,
    int nEdges, int NB)
{
    __shared__ int hist[256];
    int t = threadIdx.x;
    hist[t] = 0;
    __syncthreads();
    long long base = (long long)blockIdx.x * EPB;
    #pragma unroll
    for (int k = 0; k < EPB / 256; ++k) {
        long long e = base + k * 256 + t;
        if (e < nEdges) atomicAdd(&hist[dst[e] >> BUCKET_SHIFT], 1);
    }
    __syncthreads();
    if (t < NB) counts[t * gridDim.x + blockIdx.x] = hist[t];
}

// Phase 2a: bucket totals (NB blocks, parallel reduce over A counts each).
__global__ __launch_bounds__(256) void k_btot(
    const int* __restrict__ counts, int* __restrict__ btot, int A)
{
    __shared__ int sh[256];
    int b = blockIdx.x, t = threadIdx.x;
    int s = 0;
    for (int i = t; i < A; i += 256) s += counts[(size_t)b * A + i];
    sh[t] = s; __syncthreads();
    for (int d = 128; d > 0; d >>= 1) {
        if (t < d) sh[t] += sh[t + d];
        __syncthreads();
    }
    if (t == 0) btot[b] = sh[0];
}

// Phase 2b: one block scans NB totals -> bucketBase (exclusive).
__global__ __launch_bounds__(256) void k_scanNB(
    const int* __restrict__ btot, int* __restrict__ bucketBase,
    int* __restrict__ rowptr, int NB, int nNodes, int nEdges)
{
    __shared__ int sh[256];
    int t = threadIdx.x;
    int v = (t < NB) ? btot[t] : 0;
    sh[t] = v; __syncthreads();
    for (int d = 1; d < 256; d <<= 1) {
        int add = (t >= d) ? sh[t - d] : 0;
        __syncthreads();
        sh[t] += add;
        __syncthreads();
    }
    if (t < NB) bucketBase[t] = sh[t] - v;
    if (t == 0) { bucketBase[NB] = nEdges; rowptr[nNodes] = nEdges; }
}

// Phase 2c: per-bucket exclusive scan of its A counts + base -> start cursors.
__global__ __launch_bounds__(256) void k_cursor(
    int* __restrict__ counts, const int* __restrict__ bucketBase, int A)
{
    __shared__ int sh[256];
    int b = blockIdx.x, t = threadIdx.x;
    int run = bucketBase[b];
    for (int base = 0; base < A; base += 256) {
        int idx = base + t;
        int v = (idx < A) ? counts[(size_t)b * A + idx] : 0;
        sh[t] = v; __syncthreads();
        for (int d = 1; d < 256; d <<= 1) {
            int add = (t >= d) ? sh[t - d] : 0;
            __syncthreads();
            sh[t] += add;
            __syncthreads();
        }
        if (idx < A) counts[(size_t)b * A + idx] = run + sh[t] - v;
        run += sh[255];
        __syncthreads();
    }
}

// Phase 3: place (src,dst) pairs into bucket-contiguous binned[] (8B stores).
__global__ __launch_bounds__(256) void k_bin(
    const int* __restrict__ src, const int* __restrict__ dst,
    const int* __restrict__ counts, unsigned long long* __restrict__ binned,
    int nEdges, int NB)
{
    __shared__ int cur[256];
    int t = threadIdx.x;
    if (t < NB) cur[t] = counts[t * gridDim.x + blockIdx.x];
    __syncthreads();
    long long base = (long long)blockIdx.x * EPB;
    #pragma unroll
    for (int k = 0; k < EPB / 256; ++k) {
        long long e = base + k * 256 + t;
        if (e < nEdges) {
            int s = src[e], d = dst[e];
            int pos = atomicAdd(&cur[d >> BUCKET_SHIFT], 1);
            binned[pos] = (((unsigned long long)(unsigned)d) << 32) | (unsigned)s;
        }
    }
}

// Phase 4: per-bucket local CSR: LDS deg hist -> LDS scan -> rowptr + eidx.
__global__ __launch_bounds__(256) void k_localcsr(
    const unsigned long long* __restrict__ binned, const int* __restrict__ bucketBase,
    int* __restrict__ rowptr, int* __restrict__ eidx, int nNodes)
{
    __shared__ int ldeg[BUCKET_SZ];
    __shared__ int lscan[256];
    int t = threadIdx.x;
    ldeg[t] = 0; ldeg[t + 256] = 0;
    __syncthreads();
    int eb0 = bucketBase[blockIdx.x], eb1 = bucketBase[blockIdx.x + 1];
    int node0 = blockIdx.x << BUCKET_SHIFT;
    for (int e = eb0 + t; e < eb1; e += 256) {
        int d = (int)(binned[e] >> 32);
        atomicAdd(&ldeg[d - node0], 1);
    }
    __syncthreads();
    int d0 = ldeg[2 * t], d1 = ldeg[2 * t + 1];
    int s = d0 + d1;
    lscan[t] = s;
    __syncthreads();
    for (int d = 1; d < 256; d <<= 1) {
        int add = (t >= d) ? lscan[t - d] : 0;
        __syncthreads();
        lscan[t] += add;
        __syncthreads();
    }
    int excl = lscan[t] - s;
    ldeg[2 * t]     = excl;        // becomes local cursor
    ldeg[2 * t + 1] = excl + d0;
    int n0 = node0 + 2 * t;
    if (n0 < nNodes)     rowptr[n0]     = eb0 + excl;
    if (n0 + 1 < nNodes) rowptr[n0 + 1] = eb0 + excl + d0;
    __syncthreads();
    for (int e = eb0 + t; e < eb1; e += 256) {
        unsigned long long p = binned[e];
        int d = (int)(p >> 32), sv = (int)(p & 0xffffffffu);
        int pos = atomicAdd(&ldeg[d - node0], 1);
        eidx[eb0 + pos] = sv;
    }
}

// ---- Weight swizzle: fp32 W -> bf16 in B-fragment order -----------------
__global__ __launch_bounds__(256) void k_wconv(
    const float* __restrict__ W1, const float* __restrict__ W2,
    unsigned short* __restrict__ w1s, unsigned short* __restrict__ w2s)
{
    int idx = blockIdx.x * blockDim.x + threadIdx.x;
    if (idx < IN_F * HID_F) {            // W1: 16 ntiles x 4 ksteps
        int c = idx >> 9, L = (idx >> 3) & 63, j = idx & 7;
        int ntile = c >> 2, kstep = c & 3;
        int k = kstep * 32 + (L >> 4) * 8 + j;
        int n = ntile * 16 + (L & 15);
        w1s[idx] = f2bf(W1[k * HID_F + n]);
    }
    if (idx < HID_F * OUT_F) {           // W2: 4 ntiles x 8 ksteps
        int c = idx >> 9, L = (idx >> 3) & 63, j = idx & 7;
        int ntile = c >> 3, kstep = c & 7;
        int k = kstep * 32 + (L >> 4) * 8 + j;
        int n = ntile * 16 + (L & 15);
        w2s[idx] = f2bf(W2[k * OUT_F + n]);
    }
}

// ---- Layer-1 gather: agg[n] = xb[n] + sum xb[src] -----------------------
__global__ __launch_bounds__(256) void gather1(
    const unsigned short* __restrict__ xb, const int* __restrict__ rowptr,
    const int* __restrict__ eidx, unsigned short* __restrict__ agg, int nNodes)
{
    int n    = blockIdx.x * 4 + (threadIdx.x >> 6);
    int lane = threadIdx.x & 63;
    if (n >= nNodes) return;
    int beg = rowptr[n], end = rowptr[n + 1];
    unsigned int self = *reinterpret_cast<const unsigned int*>(
        xb + (size_t)n * IN_F + lane * 2);
    float ax = bf2f_lo(self), ay = bf2f_hi(self);
    for (int base = beg; base < end; base += 64) {
        int cnt = min(64, end - base);
        int e = (base + lane < end) ? eidx[base + lane] : 0;
        int i = 0;
        for (; i + 4 <= cnt; i += 4) {
            int s0 = __shfl(e, i), s1 = __shfl(e, i + 1);
            int s2 = __shfl(e, i + 2), s3 = __shfl(e, i + 3);
            unsigned int v0 = *reinterpret_cast<const unsigned int*>(xb + (size_t)s0 * IN_F + lane * 2);
            unsigned int v1 = *reinterpret_cast<const unsigned int*>(xb + (size_t)s1 * IN_F + lane * 2);
            unsigned int v2 = *reinterpret_cast<const unsigned int*>(xb + (size_t)s2 * IN_F + lane * 2);
            unsigned int v3 = *reinterpret_cast<const unsigned int*>(xb + (size_t)s3 * IN_F + lane * 2);
            ax += bf2f_lo(v0) + bf2f_lo(v1) + bf2f_lo(v2) + bf2f_lo(v3);
            ay += bf2f_hi(v0) + bf2f_hi(v1) + bf2f_hi(v2) + bf2f_hi(v3);
        }
        for (; i < cnt; ++i) {
            int s = __shfl(e, i);
            unsigned int v = *reinterpret_cast<const unsigned int*>(xb + (size_t)s * IN_F + lane * 2);
            ax += bf2f_lo(v); ay += bf2f_hi(v);
        }
    }
    unsigned int p = (unsigned int)f2bf(ax) | ((unsigned int)f2bf(ay) << 16);
    *reinterpret_cast<unsigned int*>(agg + (size_t)n * IN_F + lane * 2) = p;
}

// ---- GEMM1 (MFMA): h1[M,256] = agg[M,128] @ W1, bf16 out ----------------
__global__ __launch_bounds__(256) void gemm1_mfma(
    const unsigned short* __restrict__ agg, const unsigned short* __restrict__ w1s,
    unsigned short* __restrict__ h1, int nNodes)
{
    int wave = threadIdx.x >> 6, lane = threadIdx.x & 63;
    int m0 = blockIdx.x * 64 + wave * 16;
    if (m0 >= nNodes) return;
    int row = lane & 15, quad = lane >> 4;
    f32x4 acc[16] = {};
    const bf16x8* aBase = reinterpret_cast<const bf16x8*>(
        agg + (size_t)(m0 + row) * IN_F + quad * 8);
    const bf16x8* bBase = reinterpret_cast<const bf16x8*>(w1s) + lane;
    #pragma unroll
    for (int ks = 0; ks < 4; ++ks) {
        bf16x8 a = aBase[ks * 4];
        #pragma unroll
        for (int nt = 0; nt < 16; ++nt) {
            bf16x8 b = bBase[(nt * 4 + ks) * 64];
            acc[nt] = __builtin_amdgcn_mfma_f32_16x16x32_bf16(a, b, acc[nt], 0, 0, 0);
        }
    }
    size_t outBase = (size_t)(m0 + quad * 4) * HID_F + row;
    #pragma unroll
    for (int i = 0; i < 4; ++i) {
        if (m0 + quad * 4 + i >= nNodes) break;   // tail guard
        #pragma unroll
        for (int nt = 0; nt < 16; ++nt)
            h1[outBase + (size_t)i * HID_F + nt * 16] = f2bf(acc[nt][i]);
    }
}

// ---- GEMM2 (MFMA): z[M,64] = h1[M,256] @ W2, bf16 out -------------------
__global__ __launch_bounds__(256) void gemm2_mfma(
    const unsigned short* __restrict__ h1, const unsigned short* __restrict__ w2s,
    unsigned short* __restrict__ z, int nNodes)
{
    int wave = threadIdx.x >> 6, lane = threadIdx.x & 63;
    int m0 = blockIdx.x * 64 + wave * 16;
    if (m0 >= nNodes) return;
    int row = lane & 15, quad = lane >> 4;
    f32x4 acc[4] = {};
    const bf16x8* aBase = reinterpret_cast<const bf16x8*>(
        h1 + (size_t)(m0 + row) * HID_F + quad * 8);
    const bf16x8* bBase = reinterpret_cast<const bf16x8*>(w2s) + lane;
    #pragma unroll
    for (int ks = 0; ks < 8; ++ks) {
        bf16x8 a = aBase[ks * 4];
        #pragma unroll
        for (int nt = 0; nt < 4; ++nt) {
            bf16x8 b = bBase[(nt * 8 + ks) * 64];
            acc[nt] = __builtin_amdgcn_mfma_f32_16x16x32_bf16(a, b, acc[nt], 0, 0, 0);
        }
    }
    size_t outBase = (size_t)(m0 + quad * 4) * OUT_F + row;
    #pragma unroll
    for (int i = 0; i < 4; ++i) {
        if (m0 + quad * 4 + i >= nNodes) break;   // tail guard
        #pragma unroll
        for (int nt = 0; nt < 4; ++nt)
            z[outBase + (size_t)i * OUT_F + nt * 16] = f2bf(acc[nt][i]);
    }
}

// ---- Layer-2 gather (commuted): out[n] = z[n] + sum z[src] --------------
__global__ __launch_bounds__(256) void gather2(
    const unsigned short* __restrict__ z, const int* __restrict__ rowptr,
    const int* __restrict__ eidx, float* __restrict__ out, int nNodes)
{
    int n    = blockIdx.x * 4 + (threadIdx.x >> 6);
    int lane = threadIdx.x & 63;
    if (n >= nNodes) return;
    int beg = rowptr[n], end = rowptr[n + 1];
    float acc = bf2f(z[(size_t)n * OUT_F + lane]);
    for (int base = beg; base < end; base += 64) {
        int cnt = min(64, end - base);
        int e = (base + lane < end) ? eidx[base + lane] : 0;
        int i = 0;
        for (; i + 4 <= cnt; i += 4) {
            int s0 = __shfl(e, i), s1 = __shfl(e, i + 1);
            int s2 = __shfl(e, i + 2), s3 = __shfl(e, i + 3);
            unsigned short v0 = z[(size_t)s0 * OUT_F + lane];
            unsigned short v1 = z[(size_t)s1 * OUT_F + lane];
            unsigned short v2 = z[(size_t)s2 * OUT_F + lane];
            unsigned short v3 = z[(size_t)s3 * OUT_F + lane];
            acc += bf2f(v0) + bf2f(v1) + bf2f(v2) + bf2f(v3);
        }
        for (; i < cnt; ++i) {
            int s = __shfl(e, i);
            acc += bf2f(z[(size_t)s * OUT_F + lane]);
        }
    }
    out[(size_t)n * OUT_F + lane] = acc;
}

extern "C" void kernel_launch(void* const* d_in, const int* in_sizes, int n_in,
                              void* d_out, int out_size, void* d_ws, size_t ws_size,
                              hipStream_t stream) {
    const float* x  = (const float*)d_in[0];
    const int* esrc = (const int*)d_in[1];
    const int* edst = (const int*)d_in[2];
    const float* W1 = (const float*)d_in[3];
    const float* W2 = (const float*)d_in[4];
    float* out      = (float*)d_out;

    const int nNodes = in_sizes[0] / IN_F;
    const int nEdges = in_sizes[1];
    const int NB = (nNodes + BUCKET_SZ - 1) / BUCKET_SZ;   // 196 (must be <= 256)
    const int A  = (nEdges + EPB - 1) / EPB;               // 196 binning blocks

    // Workspace (~96.7 MB; 110.4 MB known-safe from R3):
    char* ws = (char*)d_ws;
    const size_t h1_b     = (size_t)nNodes * HID_F * sizeof(unsigned short);
    const size_t aggz_b   = (size_t)nNodes * IN_F * sizeof(unsigned short);
    const size_t binned_b = (size_t)nEdges * sizeof(unsigned long long);
    const size_t eidx_b   = (size_t)nEdges * sizeof(int);
    unsigned short* h1  = (unsigned short*)ws;
    unsigned short* xb  = (unsigned short*)ws;                   // alias of h1
    unsigned short* agg = (unsigned short*)(ws + h1_b);
    unsigned short* z   = (unsigned short*)(ws + h1_b);          // alias of agg
    unsigned long long* binned = (unsigned long long*)(ws + h1_b + aggz_b);
    int* eidx           = (int*)(ws + h1_b + aggz_b + binned_b);
    unsigned short* w1s = (unsigned short*)(ws + h1_b + aggz_b + binned_b + eidx_b);
    unsigned short* w2s = w1s + IN_F * HID_F;
    int* rowptr     = (int*)(w2s + HID_F * OUT_F);
    int* counts     = rowptr + (nNodes + 1);
    int* bucketBase = counts + (size_t)NB * A;
    int* btot       = bucketBase + (NB + 1);

    k_wconv<<<(IN_F * HID_F + 255) / 256, 256, 0, stream>>>(W1, W2, w1s, w2s);

    long long total8 = (long long)nNodes * IN_F / 8;
    k_xconv<<<(int)((total8 + 255) / 256), 256, 0, stream>>>(x, xb, total8);

    k_hist<<<A, 256, 0, stream>>>(edst, counts, nEdges, NB);
    k_btot<<<NB, 256, 0, stream>>>(counts, btot, A);
    k_scanNB<<<1, 256, 0, stream>>>(btot, bucketBase, rowptr, NB, nNodes, nEdges);
    k_cursor<<<NB, 256, 0, stream>>>(counts, bucketBase, A);
    k_bin<<<A, 256, 0, stream>>>(esrc, edst, counts, binned, nEdges, NB);
    k_localcsr<<<NB, 256, 0, stream>>>(binned, bucketBase, rowptr, eidx, nNodes);

    const int nBlocks = (nNodes + 3) / 4;
    const int mBlocks = (nNodes + 63) / 64;
    gather1<<<nBlocks, 256, 0, stream>>>(xb, rowptr, eidx, agg, nNodes);
    gemm1_mfma<<<mBlocks, 256, 0, stream>>>(agg, w1s, h1, nNodes);
    gemm2_mfma<<<mBlocks, 256, 0, stream>>>(h1, w2s, z, nNodes);
    gather2<<<nBlocks, 256, 0, stream>>>(z, rowptr, eidx, out, nNodes);
}